// Round 9
// baseline (1373.178 us; speedup 1.0000x reference)
//
#include <hip/hip_runtime.h>
#include <hip/hip_bf16.h>

// GCN layer: out = relu( A0 @ (X W0) + A1 @ (X W1) + bias )
// N=50000, D=128, E=800000 per adjacency, fp32 in/out, COO edges.
//
// R9:
//  - aggregate7: counting-sort key extended to (adj, src-slab, row); slab-major
//    processing keeps the chip-wide gather working set ~1 MB (fits per-XCD L2).
//    Accumulation via conflict-free ds_add into wave-private LDS acc.
//  - gemm reads fp32 x directly (in-register bf16 cvt); convert pass is W-only.
//  - fill4: 16384-edge tiles, packed per-thread state.
//
// Phases: convert_w -> gemm_mfma -> memset cur -> fill4 -> aggregate7.

#define BROWS 32                   // bucket = 32 dst rows
#define NBUCK 1563                 // ceil(50000/32)
#define BCAP 704                   // records per (bucket,adj); mean 512, +8.5 sigma
#define FT 16384                   // fill tile (edges per block)
#define NSLAB 16                   // slab = src>>12 (0..12), padded to 16
#define NKEY 1024                  // key = ((a<<4)|slab)<<5 | row_local

typedef __attribute__((ext_vector_type(8))) short bf16x8;
typedef __attribute__((ext_vector_type(4))) float f32x4;

__device__ inline unsigned short f2bf(float f) {
    union { float f; unsigned u; } v; v.f = f;
    unsigned r = v.u + 0x7fff + ((v.u >> 16) & 1);   // round-nearest-even
    return (unsigned short)(r >> 16);
}

// W0/W1 fp32 -> bf16 transposed to [n][k]; 2 blocks.
__global__ __launch_bounds__(256) void convert_w_kernel(
    const float* __restrict__ W0, const float* __restrict__ W1,
    unsigned short* __restrict__ wt0, unsigned short* __restrict__ wt1)
{
    const float* __restrict__ W = blockIdx.x ? W1 : W0;
    unsigned short* __restrict__ wt = blockIdx.x ? wt1 : wt0;
    for (int i = threadIdx.x; i < 128 * 128; i += 256) {
        int k = i >> 7, n = i & 127;
        wt[n * 128 + k] = f2bf(W[i]);
    }
}

// Wave computes 16 rows x 32 cols (two independent MFMA chains).
// A from fp32 x (in-register cvt); B from transposed bf16 W.
__global__ __launch_bounds__(256) void gemm_mfma_kernel(
    const float* __restrict__ x,
    const unsigned short* __restrict__ wt0,
    const unsigned short* __restrict__ wt1,
    unsigned short* __restrict__ pre0,
    unsigned short* __restrict__ pre1, int N)
{
    const int w = threadIdx.x >> 6;
    const int lane = threadIdx.x & 63;
    const int m0 = blockIdx.x * 16;
    const unsigned short* __restrict__ wt = blockIdx.y ? wt1 : wt0;
    unsigned short* __restrict__ pre = blockIdx.y ? pre1 : pre0;
    const int l15 = lane & 15;
    const int quad = lane >> 4;
    const int nA = w * 32 + l15;

    f32x4 c0 = {0.f, 0.f, 0.f, 0.f};
    f32x4 c1 = {0.f, 0.f, 0.f, 0.f};
#pragma unroll
    for (int k0 = 0; k0 < 128; k0 += 32) {
        const float* xp = &x[(m0 + l15) * 128 + k0 + quad * 8];
        float4 v0 = *(const float4*)xp;
        float4 v1 = *(const float4*)(xp + 4);
        bf16x8 a;
        ((short*)&a)[0] = (short)f2bf(v0.x);
        ((short*)&a)[1] = (short)f2bf(v0.y);
        ((short*)&a)[2] = (short)f2bf(v0.z);
        ((short*)&a)[3] = (short)f2bf(v0.w);
        ((short*)&a)[4] = (short)f2bf(v1.x);
        ((short*)&a)[5] = (short)f2bf(v1.y);
        ((short*)&a)[6] = (short)f2bf(v1.z);
        ((short*)&a)[7] = (short)f2bf(v1.w);
        bf16x8 b0 = *(const bf16x8*)&wt[nA * 128 + k0 + quad * 8];
        bf16x8 b1 = *(const bf16x8*)&wt[(nA + 16) * 128 + k0 + quad * 8];
        c0 = __builtin_amdgcn_mfma_f32_16x16x32_bf16(a, b0, c0, 0, 0, 0);
        c1 = __builtin_amdgcn_mfma_f32_16x16x32_bf16(a, b1, c1, 0, 0, 0);
    }
#pragma unroll
    for (int i = 0; i < 4; ++i) {
        int row = m0 + quad * 4 + i;              // N % 16 == 0
        pre[row * 128 + w * 32 + l15] = f2bf(c0[i]);
        pre[row * 128 + w * 32 + 16 + l15] = f2bf(c1[i]);
    }
}

// Fixed-capacity binned fill, bin = (dst>>5)*2 + adj. Per-record rank from
// LDS hist atomicAdd; one global cursor add per (block,key) -> run-contiguous
// writes (runs ~10.5 recs). Record = { row_local<<16 | src, val }.
__global__ __launch_bounds__(1024) void fill4_kernel(
    const int* __restrict__ ei0, const int* __restrict__ ei1,
    const float* __restrict__ ev0, const float* __restrict__ ev1,
    int* __restrict__ cur, int2* __restrict__ recs, int E)
{
    const int a = blockIdx.y;
    const int* __restrict__ ei = a ? ei1 : ei0;
    const float* __restrict__ ev = a ? ev1 : ev0;

    __shared__ int lcnt[NBUCK];
    __shared__ int gbase[NBUCK];
    __shared__ int glim[NBUCK];
    for (int k = threadIdx.x; k < NBUCK; k += 1024) lcnt[k] = 0;
    __syncthreads();

    const int e0 = blockIdx.x * FT;
    unsigned ds[16];
    float val[16];
    short rank[16];
#pragma unroll
    for (int j = 0; j < 16; ++j) {
        int e = e0 + j * 1024 + threadIdx.x;
        if (e < E) {
            int d = ei[e];
            int s = ei[E + e];
            ds[j] = ((unsigned)d << 16) | (unsigned)s;   // d < 50000 < 65536
            val[j] = ev[e];
            rank[j] = (short)atomicAdd(&lcnt[d >> 5], 1);
        } else ds[j] = 0xffffffffu;                      // d=65535 impossible
    }
    __syncthreads();

    for (int k = threadIdx.x; k < NBUCK; k += 1024) {
        int c = lcnt[k];
        int base = 0, lim = 0;
        if (c > 0) {
            int bin = k * 2 + a;
            int b0 = atomicAdd(&cur[bin], c);
            lim = BCAP - b0; if (lim < 0) lim = 0;       // overflow guard
            base = bin * BCAP + b0;
        }
        gbase[k] = base;
        glim[k] = lim;
    }
    __syncthreads();

#pragma unroll
    for (int j = 0; j < 16; ++j) {
        if (ds[j] != 0xffffffffu) {
            int key = ds[j] >> 21;                       // dst>>5
            int r = rank[j];
            if (r < glim[key]) {
                int rl = (ds[j] >> 16) & 31;
                recs[gbase[key] + r] =
                    make_int2((rl << 16) | (ds[j] & 0xffff), __float_as_int(val[j]));
            }
        }
    }
}

// One block per 32-row bucket (256 thr = 4 waves, rows wv*8..wv*8+7).
// Counting-sort records by key=(adj, src>>12, row) into LDS, then slab-major
// processing: per record one bf16x2 gather dword/lane (slab L2-resident) and
// two conflict-free ds_add into the wave-private fp32 accumulator.
__global__ __launch_bounds__(256) void aggregate7_kernel(
    const int* __restrict__ cur, const int2* __restrict__ recs,
    const unsigned short* __restrict__ pre0,
    const unsigned short* __restrict__ pre1,
    const float* __restrict__ bias,
    float* __restrict__ out, int N)
{
    __shared__ int2 srec[2 * BCAP];      // 11.3 KB sorted records
    __shared__ int lstart[NKEY + 1];     // 4.1 KB
    __shared__ int lcur[NKEY];           // 4 KB (counts, then cursors)
    __shared__ int part[256];            // 1 KB scan partials
    __shared__ float sacc[BROWS * 128];  // 16 KB accumulator

    const int b = blockIdx.x;
    const int tid = threadIdx.x;
    int n0 = cur[2 * b];     if (n0 > BCAP) n0 = BCAP;
    int n1 = cur[2 * b + 1]; if (n1 > BCAP) n1 = BCAP;
    const int total = n0 + n1;
    const int base0 = (2 * b) * BCAP, base1 = (2 * b + 1) * BCAP;

    for (int k = tid; k < NKEY; k += 256) lcur[k] = 0;
#pragma unroll
    for (int i = 0; i < 16; ++i) sacc[tid + i * 256] = 0.f;
    __syncthreads();

    // pass 1: count by key
    for (int i = tid; i < total; i += 256) {
        int2 r = (i < n0) ? recs[base0 + i] : recs[base1 + i - n0];
        int a = (i >= n0);
        int key = (((a << 4) | ((r.x & 0xffff) >> 12)) << 5) | (r.x >> 16);
        atomicAdd(&lcur[key], 1);
    }
    __syncthreads();

    // exclusive scan of 1024 counters (4 per thread + 256-wide LDS scan)
    const int k4 = tid * 4;
    int c0 = lcur[k4], c1 = lcur[k4 + 1], c2 = lcur[k4 + 2], c3 = lcur[k4 + 3];
    int tsum = c0 + c1 + c2 + c3;
    part[tid] = tsum;
    __syncthreads();
    for (int o = 1; o < 256; o <<= 1) {
        int t = (tid >= o) ? part[tid - o] : 0;
        __syncthreads();
        part[tid] += t;
        __syncthreads();
    }
    int run = part[tid] - tsum;
    lstart[k4] = run;     lcur[k4] = run;     run += c0;
    lstart[k4 + 1] = run; lcur[k4 + 1] = run; run += c1;
    lstart[k4 + 2] = run; lcur[k4 + 2] = run; run += c2;
    lstart[k4 + 3] = run; lcur[k4 + 3] = run; run += c3;
    if (tid == 255) lstart[NKEY] = run;
    __syncthreads();

    // pass 2: scatter sorted into LDS
    for (int i = tid; i < total; i += 256) {
        int2 r = (i < n0) ? recs[base0 + i] : recs[base1 + i - n0];
        int a = (i >= n0);
        int key = (((a << 4) | ((r.x & 0xffff) >> 12)) << 5) | (r.x >> 16);
        srec[atomicAdd(&lcur[key], 1)] = r;
    }
    __syncthreads();

    // slab-major processing
    const int wv = tid >> 6;
    const int lane = tid & 63;
    const int q = (lane >> 4) & 1;
    const int colA = 2 * lane + q;        // conflict-free (32 banks x 2 lanes)
    const int colB = 2 * lane + 1 - q;

#define PROC(r, u) {                                                  \
        float v = __int_as_float((r).y);                              \
        float plo = __uint_as_float((u) << 16);                       \
        float phi = __uint_as_float((u) & 0xffff0000u);               \
        float vA = q ? phi : plo;                                     \
        float vB = q ? plo : phi;                                     \
        int rw = ((r).x >> 16) << 7;                                  \
        atomicAdd(&sacc[rw + colA], v * vA);                          \
        atomicAdd(&sacc[rw + colB], v * vB);                          \
    }

#pragma unroll
    for (int a = 0; a < 2; ++a) {
        const unsigned short* __restrict__ pre = a ? pre1 : pre0;
        for (int slab = 0; slab < 13; ++slab) {
            const int k0 = (((a << 4) | slab) << 5) | (wv * 8);
            const int s = lstart[k0];
            const int e = lstart[k0 + 8];   // rows are low key bits: contiguous
            int j = s;
            for (; j + 4 <= e; j += 4) {
                int2 r0 = srec[j], r1 = srec[j + 1], r2 = srec[j + 2], r3 = srec[j + 3];
                unsigned u0 = *(const unsigned*)&pre[(r0.x & 0xffff) * 128 + 2 * lane];
                unsigned u1 = *(const unsigned*)&pre[(r1.x & 0xffff) * 128 + 2 * lane];
                unsigned u2 = *(const unsigned*)&pre[(r2.x & 0xffff) * 128 + 2 * lane];
                unsigned u3 = *(const unsigned*)&pre[(r3.x & 0xffff) * 128 + 2 * lane];
                PROC(r0, u0); PROC(r1, u1); PROC(r2, u2); PROC(r3, u3);
            }
            for (; j < e; ++j) {
                int2 r0 = srec[j];
                unsigned u0 = *(const unsigned*)&pre[(r0.x & 0xffff) * 128 + 2 * lane];
                PROC(r0, u0);
            }
        }
    }
#undef PROC
    __syncthreads();

    // epilogue: bias + relu, one float4 store per 32 cols
    const int row0 = b * BROWS;
#pragma unroll
    for (int i = 0; i < 4; ++i) {
        int t = tid + i * 256;
        int r = t >> 5, c4 = (t & 31) << 2;
        int row = row0 + r;
        if (row < N) {
            float4 vv = *(float4*)&sacc[r * 128 + c4];
            vv.x = fmaxf(vv.x + bias[c4 + 0], 0.f);
            vv.y = fmaxf(vv.y + bias[c4 + 1], 0.f);
            vv.z = fmaxf(vv.z + bias[c4 + 2], 0.f);
            vv.w = fmaxf(vv.w + bias[c4 + 3], 0.f);
            *(float4*)&out[row * 128 + c4] = vv;
        }
    }
}

extern "C" void kernel_launch(void* const* d_in, const int* in_sizes, int n_in,
                              void* d_out, int out_size, void* d_ws, size_t ws_size,
                              hipStream_t stream) {
    const float* x    = (const float*)d_in[0];
    const float* W0   = (const float*)d_in[1];
    const float* W1   = (const float*)d_in[2];
    const float* bias = (const float*)d_in[3];
    const float* ev0  = (const float*)d_in[4];
    const float* ev1  = (const float*)d_in[5];
    const int*   ei0  = (const int*)d_in[6];
    const int*   ei1  = (const int*)d_in[7];
    float* out = (float*)d_out;

    const int N = in_sizes[0] / 128;      // 50000
    const int E = in_sizes[4];            // 800000
    const int NX = N * 128;
    const int NBINS2 = NBUCK * 2;         // 3126

    // Workspace layout
    char* w = (char*)d_ws;
    unsigned short* pre0 = (unsigned short*)w;  w += (size_t)NX * 2;
    unsigned short* pre1 = (unsigned short*)w;  w += (size_t)NX * 2;
    unsigned short* wt0  = (unsigned short*)w;  w += (size_t)128 * 128 * 2;
    unsigned short* wt1  = (unsigned short*)w;  w += (size_t)128 * 128 * 2;
    int* cur = (int*)w;                         w += (size_t)NBINS2 * 4;
    int2* recs = (int2*)w;                      w += (size_t)NBINS2 * BCAP * 8;

    // Phase 0: W -> bf16 transposed (2 blocks)
    convert_w_kernel<<<2, 256, 0, stream>>>(W0, W1, wt0, wt1);

    // Phase 1: MFMA GEMMs (fp32 x read, fp32 accumulate, bf16 store)
    dim3 ggrid(N / 16, 2);
    gemm_mfma_kernel<<<ggrid, 256, 0, stream>>>(x, wt0, wt1, pre0, pre1, N);

    // Phase 2: zero bin cursors, binned fill
    hipMemsetAsync(cur, 0, (size_t)NBINS2 * 4, stream);
    dim3 fgrid((E + FT - 1) / FT, 2);
    fill4_kernel<<<fgrid, 1024, 0, stream>>>(ei0, ei1, ev0, ev1, cur, recs, E);

    // Phase 3: slab-major bucketed aggregation + bias + relu
    aggregate7_kernel<<<NBUCK, 256, 0, stream>>>(cur, recs, pre0, pre1,
                                                 bias, out, N);
}

// Round 10
// 250.009 us; speedup vs baseline: 5.4925x; 5.4925x over previous
//
#include <hip/hip_runtime.h>
#include <hip/hip_bf16.h>

// GCN layer: out = relu( A0 @ (X W0) + A1 @ (X W1) + bias )
// N=50000, D=128, E=800000 per adjacency, fp32 in/out, COO edges.
//
// R10 (revert R9's LDS-atomic gather; keep its wins):
//   convert_w    W0,W1 -> bf16 transposed (2 blocks)
//   gemm_fused   one block = 16 rows x both adjacencies (512 thr); reads fp32
//                x once, in-register bf16 cvt, MFMA 16x16x32, bf16 pre store
//   fill4        fixed-capacity 32-row bins, run-contiguous record writes
//   aggregate8   R8's register-accumulate sorted gather, 32-row buckets,
//                256 thr, ~15 KB LDS (higher occupancy than R8's 64-row/512).
// NEVER use fp32 LDS atomics in the per-record loop (R4: 1234 us, R9: 1216 us).

#define BROWS 32                   // bucket = 32 dst rows
#define NBUCK 1563                 // ceil(50000/32)
#define BCAP 704                   // records per (bucket,adj); mean 512, +8.5 sigma
#define ACAP (2 * BCAP)
#define FT 16384                   // fill tile (edges per block)

typedef __attribute__((ext_vector_type(8))) short bf16x8;
typedef __attribute__((ext_vector_type(4))) float f32x4;

__device__ inline unsigned short f2bf(float f) {
    union { float f; unsigned u; } v; v.f = f;
    unsigned r = v.u + 0x7fff + ((v.u >> 16) & 1);   // round-nearest-even
    return (unsigned short)(r >> 16);
}

// W0/W1 fp32 -> bf16 transposed to [n][k]; 2 blocks.
__global__ __launch_bounds__(256) void convert_w_kernel(
    const float* __restrict__ W0, const float* __restrict__ W1,
    unsigned short* __restrict__ wt0, unsigned short* __restrict__ wt1)
{
    const float* __restrict__ W = blockIdx.x ? W1 : W0;
    unsigned short* __restrict__ wt = blockIdx.x ? wt1 : wt0;
    for (int i = threadIdx.x; i < 128 * 128; i += 256) {
        int k = i >> 7, n = i & 127;
        wt[n * 128 + k] = f2bf(W[i]);
    }
}

// One block: 16 x-rows, BOTH adjacencies. 8 waves: waves 0-3 -> W0 cols,
// waves 4-7 -> W1 cols (32 cols each). x read once (L1-shared across waves).
// A: m=lane&15, k=quad*8+j ; B(from Wt): n=lane&15, k=quad*8+j ;
// C/D: col=lane&15, row=quad*4+reg.
__global__ __launch_bounds__(512) void gemm_fused_kernel(
    const float* __restrict__ x,
    const unsigned short* __restrict__ wt0,
    const unsigned short* __restrict__ wt1,
    unsigned short* __restrict__ pre0,
    unsigned short* __restrict__ pre1, int N)
{
    const int w = threadIdx.x >> 6;
    const int lane = threadIdx.x & 63;
    const int adj = w >> 2;
    const int wq = w & 3;
    const int m0 = blockIdx.x * 16;
    const unsigned short* __restrict__ wt = adj ? wt1 : wt0;
    unsigned short* __restrict__ pre = adj ? pre1 : pre0;
    const int l15 = lane & 15;
    const int quad = lane >> 4;
    const int nA = wq * 32 + l15;

    f32x4 c0 = {0.f, 0.f, 0.f, 0.f};
    f32x4 c1 = {0.f, 0.f, 0.f, 0.f};
#pragma unroll
    for (int k0 = 0; k0 < 128; k0 += 32) {
        const float* xp = &x[(m0 + l15) * 128 + k0 + quad * 8];
        float4 v0 = *(const float4*)xp;
        float4 v1 = *(const float4*)(xp + 4);
        bf16x8 a;
        ((short*)&a)[0] = (short)f2bf(v0.x);
        ((short*)&a)[1] = (short)f2bf(v0.y);
        ((short*)&a)[2] = (short)f2bf(v0.z);
        ((short*)&a)[3] = (short)f2bf(v0.w);
        ((short*)&a)[4] = (short)f2bf(v1.x);
        ((short*)&a)[5] = (short)f2bf(v1.y);
        ((short*)&a)[6] = (short)f2bf(v1.z);
        ((short*)&a)[7] = (short)f2bf(v1.w);
        bf16x8 b0 = *(const bf16x8*)&wt[nA * 128 + k0 + quad * 8];
        bf16x8 b1 = *(const bf16x8*)&wt[(nA + 16) * 128 + k0 + quad * 8];
        c0 = __builtin_amdgcn_mfma_f32_16x16x32_bf16(a, b0, c0, 0, 0, 0);
        c1 = __builtin_amdgcn_mfma_f32_16x16x32_bf16(a, b1, c1, 0, 0, 0);
    }
#pragma unroll
    for (int i = 0; i < 4; ++i) {
        int row = m0 + quad * 4 + i;              // N % 16 == 0
        pre[row * 128 + wq * 32 + l15] = f2bf(c0[i]);
        pre[row * 128 + wq * 32 + 16 + l15] = f2bf(c1[i]);
    }
}

// Fixed-capacity binned fill, bin = (dst>>5)*2 + adj. Per-record rank from
// LDS int hist atomicAdd; one global cursor add per (block,key) ->
// run-contiguous writes. Record = { row_local<<16 | src, val }.
__global__ __launch_bounds__(1024) void fill4_kernel(
    const int* __restrict__ ei0, const int* __restrict__ ei1,
    const float* __restrict__ ev0, const float* __restrict__ ev1,
    int* __restrict__ cur, int2* __restrict__ recs, int E)
{
    const int a = blockIdx.y;
    const int* __restrict__ ei = a ? ei1 : ei0;
    const float* __restrict__ ev = a ? ev1 : ev0;

    __shared__ int lcnt[NBUCK];
    __shared__ int gbase[NBUCK];
    __shared__ int glim[NBUCK];
    for (int k = threadIdx.x; k < NBUCK; k += 1024) lcnt[k] = 0;
    __syncthreads();

    const int e0 = blockIdx.x * FT;
    unsigned ds[16];
    float val[16];
    short rank[16];
#pragma unroll
    for (int j = 0; j < 16; ++j) {
        int e = e0 + j * 1024 + threadIdx.x;
        if (e < E) {
            int d = ei[e];
            int s = ei[E + e];
            ds[j] = ((unsigned)d << 16) | (unsigned)s;   // d < 50000 < 65536
            val[j] = ev[e];
            rank[j] = (short)atomicAdd(&lcnt[d >> 5], 1);
        } else ds[j] = 0xffffffffu;                      // d=65535 impossible
    }
    __syncthreads();

    for (int k = threadIdx.x; k < NBUCK; k += 1024) {
        int c = lcnt[k];
        int base = 0, lim = 0;
        if (c > 0) {
            int bin = k * 2 + a;
            int b0 = atomicAdd(&cur[bin], c);
            lim = BCAP - b0; if (lim < 0) lim = 0;       // overflow guard
            base = bin * BCAP + b0;
        }
        gbase[k] = base;
        glim[k] = lim;
    }
    __syncthreads();

#pragma unroll
    for (int j = 0; j < 16; ++j) {
        if (ds[j] != 0xffffffffu) {
            int key = ds[j] >> 21;                       // dst>>5
            int r = rank[j];
            if (r < glim[key]) {
                int rl = (ds[j] >> 16) & 31;
                recs[gbase[key] + r] =
                    make_int2((rl << 16) | (ds[j] & 0xffff), __float_as_int(val[j]));
            }
        }
    }
}

// One block per 32-row bucket (256 thr = 4 waves, wave wv -> rows wv*8..+7).
// Stage records in LDS, counting-sort indices by key=(adj<<5)|row, then
// 4x-unrolled independent gathers of bf16 pre rows, register accumulate,
// fused bias+relu writeout. No atomics in the gather loop.
__global__ __launch_bounds__(256) void aggregate8_kernel(
    const int* __restrict__ cur, const int2* __restrict__ recs,
    const unsigned short* __restrict__ pre0,
    const unsigned short* __restrict__ pre1,
    const float* __restrict__ bias,
    float* __restrict__ out, int N)
{
    __shared__ int2 srec[ACAP];             // 11.3 KB
    __shared__ unsigned short sidx[ACAP];   // 2.8 KB
    __shared__ int lcnt[64];
    __shared__ int lstart[64];
    __shared__ int lcur[64];

    const int b = blockIdx.x;
    const int tid = threadIdx.x;

    int n0 = cur[2 * b];     if (n0 > BCAP) n0 = BCAP;
    int n1 = cur[2 * b + 1]; if (n1 > BCAP) n1 = BCAP;
    const int total = n0 + n1;
    const int base0 = (2 * b) * BCAP, base1 = (2 * b + 1) * BCAP;

    if (tid < 64) lcnt[tid] = 0;
    __syncthreads();

    // stage + per-(adj,row) counts (int LDS atomics, 2 per thread-iter: fine)
    for (int i = tid; i < total; i += 256) {
        int2 r = (i < n0) ? recs[base0 + i] : recs[base1 + i - n0];
        srec[i] = r;
        int a = (i >= n0);
        atomicAdd(&lcnt[(a << 5) | (r.x >> 16)], 1);
    }
    __syncthreads();

    // wave 0: 64-wide shfl exclusive scan of the 64 counters
    if (tid < 64) {
        int cme = lcnt[tid];
        int p = cme;
#pragma unroll
        for (int o = 1; o < 64; o <<= 1) {
            int t = __shfl_up(p, o);
            if (tid >= o) p += t;
        }
        lstart[tid] = p - cme;
        lcur[tid] = p - cme;
    }
    __syncthreads();

    // scatter indices sorted by key
    for (int i = tid; i < total; i += 256) {
        int a = (i >= n0);
        int key = (a << 5) | (srec[i].x >> 16);
        sidx[atomicAdd(&lcur[key], 1)] = (unsigned short)i;
    }
    __syncthreads();

    // gather: wave wv owns rows wv*8 .. wv*8+7
    const int wv = tid >> 6;
    const int lane = tid & 63;
    const float2 bi = *(const float2*)&bias[lane * 2];

    for (int t = 0; t < 8; ++t) {
        const int rl = wv * 8 + t;
        float2 acc = make_float2(0.f, 0.f);
#pragma unroll
        for (int a = 0; a < 2; ++a) {
            const unsigned short* __restrict__ pre = a ? pre1 : pre0;
            const int key = (a << 5) | rl;
            const int s = lstart[key];
            const int n = lcnt[key];
            int j = 0;
            for (; j + 4 <= n; j += 4) {
                int i0 = sidx[s + j + 0];
                int i1 = sidx[s + j + 1];
                int i2 = sidx[s + j + 2];
                int i3 = sidx[s + j + 3];
                int2 r0 = srec[i0], r1 = srec[i1], r2 = srec[i2], r3 = srec[i3];
                unsigned u0 = *(const unsigned*)&pre[(r0.x & 0xffff) * 128 + 2 * lane];
                unsigned u1 = *(const unsigned*)&pre[(r1.x & 0xffff) * 128 + 2 * lane];
                unsigned u2 = *(const unsigned*)&pre[(r2.x & 0xffff) * 128 + 2 * lane];
                unsigned u3 = *(const unsigned*)&pre[(r3.x & 0xffff) * 128 + 2 * lane];
                float v0 = __int_as_float(r0.y), v1 = __int_as_float(r1.y);
                float v2 = __int_as_float(r2.y), v3 = __int_as_float(r3.y);
                acc.x = fmaf(v0, __uint_as_float(u0 << 16), acc.x);
                acc.y = fmaf(v0, __uint_as_float(u0 & 0xffff0000u), acc.y);
                acc.x = fmaf(v1, __uint_as_float(u1 << 16), acc.x);
                acc.y = fmaf(v1, __uint_as_float(u1 & 0xffff0000u), acc.y);
                acc.x = fmaf(v2, __uint_as_float(u2 << 16), acc.x);
                acc.y = fmaf(v2, __uint_as_float(u2 & 0xffff0000u), acc.y);
                acc.x = fmaf(v3, __uint_as_float(u3 << 16), acc.x);
                acc.y = fmaf(v3, __uint_as_float(u3 & 0xffff0000u), acc.y);
            }
            for (; j < n; ++j) {
                int2 r0 = srec[sidx[s + j]];
                unsigned u0 = *(const unsigned*)&pre[(r0.x & 0xffff) * 128 + 2 * lane];
                float v0 = __int_as_float(r0.y);
                acc.x = fmaf(v0, __uint_as_float(u0 << 16), acc.x);
                acc.y = fmaf(v0, __uint_as_float(u0 & 0xffff0000u), acc.y);
            }
        }
        int row = b * BROWS + rl;
        if (row < N) {
            float2 o;
            o.x = fmaxf(acc.x + bi.x, 0.f);
            o.y = fmaxf(acc.y + bi.y, 0.f);
            *(float2*)&out[row * 128 + 2 * lane] = o;
        }
    }
}

extern "C" void kernel_launch(void* const* d_in, const int* in_sizes, int n_in,
                              void* d_out, int out_size, void* d_ws, size_t ws_size,
                              hipStream_t stream) {
    const float* x    = (const float*)d_in[0];
    const float* W0   = (const float*)d_in[1];
    const float* W1   = (const float*)d_in[2];
    const float* bias = (const float*)d_in[3];
    const float* ev0  = (const float*)d_in[4];
    const float* ev1  = (const float*)d_in[5];
    const int*   ei0  = (const int*)d_in[6];
    const int*   ei1  = (const int*)d_in[7];
    float* out = (float*)d_out;

    const int N = in_sizes[0] / 128;      // 50000
    const int E = in_sizes[4];            // 800000
    const int NX = N * 128;
    const int NBINS2 = NBUCK * 2;         // 3126

    // Workspace layout
    char* w = (char*)d_ws;
    unsigned short* pre0 = (unsigned short*)w;  w += (size_t)NX * 2;
    unsigned short* pre1 = (unsigned short*)w;  w += (size_t)NX * 2;
    unsigned short* wt0  = (unsigned short*)w;  w += (size_t)128 * 128 * 2;
    unsigned short* wt1  = (unsigned short*)w;  w += (size_t)128 * 128 * 2;
    int* cur = (int*)w;                         w += (size_t)NBINS2 * 4;
    int2* recs = (int2*)w;                      w += (size_t)NBINS2 * BCAP * 8;

    // Phase 0: W -> bf16 transposed (2 blocks)
    convert_w_kernel<<<2, 256, 0, stream>>>(W0, W1, wt0, wt1);

    // Phase 1: fused MFMA GEMM (x read once, both adjacencies per block)
    gemm_fused_kernel<<<N / 16, 512, 0, stream>>>(x, wt0, wt1, pre0, pre1, N);

    // Phase 2: zero bin cursors, binned fill
    hipMemsetAsync(cur, 0, (size_t)NBINS2 * 4, stream);
    dim3 fgrid((E + FT - 1) / FT, 2);
    fill4_kernel<<<fgrid, 1024, 0, stream>>>(ei0, ei1, ev0, ev1, cur, recs, E);

    // Phase 3: bucket-sorted gather aggregation + bias + relu
    aggregate8_kernel<<<NBUCK, 256, 0, stream>>>(cur, recs, pre0, pre1,
                                                 bias, out, N);
}

// Round 11
// 238.973 us; speedup vs baseline: 5.7462x; 1.0462x over previous
//
#include <hip/hip_runtime.h>
#include <hip/hip_bf16.h>

// GCN layer: out = relu( A0 @ (X W0) + A1 @ (X W1) + bias )
// N=50000, D=128, E=800000 per adjacency, fp32 in/out, COO edges.
//
// R11:
//  - unified pre buffer: row = adj*65536 + src; records carry adj bit ->
//    aggregate sorts on 32 keys (row only), scatters full int2 records
//    (no index indirection), gathers 8x-unrolled with both adjacencies
//    merged per dst row. Register accumulate only (NO fp32 LDS atomics:
//    R4 1234us, R9 1216us).
//  - gemm: C staged through per-wave LDS tile -> 16-B coalesced pre stores.
//  - fill: FT=4096, grid (196,2)=392 blocks (CU coverage vs 98 blocks).
//  - cur zeroing folded into convert_w (memset dispatch dropped).

#define BROWS 32                   // bucket = 32 dst rows
#define NBUCK 1563                 // ceil(50000/32)
#define BCAP 704                   // records per (bucket,adj); mean 512, +8.5 sigma
#define ACAP (2 * BCAP)
#define FT 4096                    // fill tile (edges per block)
#define PREROWS 65536              // adj stride in unified pre

typedef __attribute__((ext_vector_type(8))) short bf16x8;
typedef __attribute__((ext_vector_type(4))) float f32x4;

__device__ inline unsigned short f2bf(float f) {
    union { float f; unsigned u; } v; v.f = f;
    unsigned r = v.u + 0x7fff + ((v.u >> 16) & 1);   // round-nearest-even
    return (unsigned short)(r >> 16);
}

// blocks 0,1: W0/W1 fp32 -> bf16 transposed [n][k]. blocks 2,3: zero cur.
__global__ __launch_bounds__(256) void convert_w_kernel(
    const float* __restrict__ W0, const float* __restrict__ W1,
    unsigned short* __restrict__ wt0, unsigned short* __restrict__ wt1,
    int* __restrict__ cur, int ncur)
{
    if (blockIdx.x >= 2) {
        int half = (ncur + 1) / 2;
        int base = (blockIdx.x - 2) * half;
        for (int i = threadIdx.x; i < half; i += 256)
            if (base + i < ncur) cur[base + i] = 0;
        return;
    }
    const float* __restrict__ W = blockIdx.x ? W1 : W0;
    unsigned short* __restrict__ wt = blockIdx.x ? wt1 : wt0;
    for (int i = threadIdx.x; i < 128 * 128; i += 256) {
        int k = i >> 7, n = i & 127;
        wt[n * 128 + k] = f2bf(W[i]);
    }
}

// One block: 16 x-rows, BOTH adjacencies. Waves 0-3 -> W0 cols, 4-7 -> W1.
// A: m=lane&15, k=quad*8+j ; B(from Wt): n=lane&15, k=quad*8+j ;
// C/D: col=lane&15, row=quad*4+reg. C staged via LDS -> 16-B global stores.
__global__ __launch_bounds__(512) void gemm_fused_kernel(
    const float* __restrict__ x,
    const unsigned short* __restrict__ wt0,
    const unsigned short* __restrict__ wt1,
    unsigned short* __restrict__ pre,    // unified: adj*PREROWS + row
    int N)
{
    __shared__ short ctile[8][16][40];   // per-wave 16x32 C tile (+pad)

    const int w = threadIdx.x >> 6;
    const int lane = threadIdx.x & 63;
    const int adj = w >> 2;
    const int wq = w & 3;
    const int m0 = blockIdx.x * 16;
    const unsigned short* __restrict__ wt = adj ? wt1 : wt0;
    unsigned short* __restrict__ po = pre + (size_t)adj * PREROWS * 128;
    const int l15 = lane & 15;
    const int quad = lane >> 4;
    const int nA = wq * 32 + l15;

    f32x4 c0 = {0.f, 0.f, 0.f, 0.f};
    f32x4 c1 = {0.f, 0.f, 0.f, 0.f};
#pragma unroll
    for (int k0 = 0; k0 < 128; k0 += 32) {
        const float* xp = &x[(m0 + l15) * 128 + k0 + quad * 8];
        float4 v0 = *(const float4*)xp;
        float4 v1 = *(const float4*)(xp + 4);
        bf16x8 a;
        ((short*)&a)[0] = (short)f2bf(v0.x);
        ((short*)&a)[1] = (short)f2bf(v0.y);
        ((short*)&a)[2] = (short)f2bf(v0.z);
        ((short*)&a)[3] = (short)f2bf(v0.w);
        ((short*)&a)[4] = (short)f2bf(v1.x);
        ((short*)&a)[5] = (short)f2bf(v1.y);
        ((short*)&a)[6] = (short)f2bf(v1.z);
        ((short*)&a)[7] = (short)f2bf(v1.w);
        bf16x8 b0 = *(const bf16x8*)&wt[nA * 128 + k0 + quad * 8];
        bf16x8 b1 = *(const bf16x8*)&wt[(nA + 16) * 128 + k0 + quad * 8];
        c0 = __builtin_amdgcn_mfma_f32_16x16x32_bf16(a, b0, c0, 0, 0, 0);
        c1 = __builtin_amdgcn_mfma_f32_16x16x32_bf16(a, b1, c1, 0, 0, 0);
    }

    // stage C into wave-private LDS tile (wave-internal dep: no barrier)
#pragma unroll
    for (int i = 0; i < 4; ++i) {
        ctile[w][quad * 4 + i][l15]      = (short)f2bf(c0[i]);
        ctile[w][quad * 4 + i][16 + l15] = (short)f2bf(c1[i]);
    }
    // read back coalesced: lane -> row lane>>2, col group (lane&3)*8
    const int rr = lane >> 2, cg = (lane & 3) * 8;
    ushort4 s0 = *(ushort4*)&ctile[w][rr][cg];
    ushort4 s1 = *(ushort4*)&ctile[w][rr][cg + 4];
    int row = m0 + rr;                        // N % 16 == 0, always < N
    *(ushort4*)&po[row * 128 + wq * 32 + cg] = s0;
    *(ushort4*)&po[row * 128 + wq * 32 + cg + 4] = s1;
}

// Fixed-capacity binned fill, bin = (dst>>5)*2 + adj. Per-record rank from
// LDS int hist atomicAdd; one global cursor add per (block,key) ->
// run-contiguous writes. Record = { rl<<17 | adj<<16 | src, val }.
__global__ __launch_bounds__(1024) void fill4_kernel(
    const int* __restrict__ ei0, const int* __restrict__ ei1,
    const float* __restrict__ ev0, const float* __restrict__ ev1,
    int* __restrict__ cur, int2* __restrict__ recs, int E)
{
    const int a = blockIdx.y;
    const int* __restrict__ ei = a ? ei1 : ei0;
    const float* __restrict__ ev = a ? ev1 : ev0;

    __shared__ int lcnt[NBUCK];
    __shared__ int gbase[NBUCK];
    __shared__ int glim[NBUCK];
    for (int k = threadIdx.x; k < NBUCK; k += 1024) lcnt[k] = 0;
    __syncthreads();

    const int e0 = blockIdx.x * FT;
    unsigned ds[4];
    float val[4];
    short rank[4];
#pragma unroll
    for (int j = 0; j < 4; ++j) {
        int e = e0 + j * 1024 + threadIdx.x;
        if (e < E) {
            int d = ei[e];
            int s = ei[E + e];
            ds[j] = ((unsigned)d << 16) | (unsigned)s;   // d < 50000 < 65536
            val[j] = ev[e];
            rank[j] = (short)atomicAdd(&lcnt[d >> 5], 1);
        } else ds[j] = 0xffffffffu;                      // d=65535 impossible
    }
    __syncthreads();

    for (int k = threadIdx.x; k < NBUCK; k += 1024) {
        int c = lcnt[k];
        int base = 0, lim = 0;
        if (c > 0) {
            int bin = k * 2 + a;
            int b0 = atomicAdd(&cur[bin], c);
            lim = BCAP - b0; if (lim < 0) lim = 0;       // overflow guard
            base = bin * BCAP + b0;
        }
        gbase[k] = base;
        glim[k] = lim;
    }
    __syncthreads();

#pragma unroll
    for (int j = 0; j < 4; ++j) {
        if (ds[j] != 0xffffffffu) {
            int key = ds[j] >> 21;                       // dst>>5
            int r = rank[j];
            if (r < glim[key]) {
                int rl = (ds[j] >> 16) & 31;
                recs[gbase[key] + r] =
                    make_int2((rl << 17) | (a << 16) | (ds[j] & 0xffff),
                              __float_as_int(val[j]));
            }
        }
    }
}

// One block per 32-row bucket (256 thr = 4 waves, wave wv -> rows wv*8..+7).
// Stage records in LDS, counting-sort FULL records by row (32 keys), then
// 8x-unrolled independent gathers from the unified pre, register accumulate,
// fused bias+relu writeout.
__global__ __launch_bounds__(256, 6) void aggregate9_kernel(
    const int* __restrict__ cur, const int2* __restrict__ recs,
    const unsigned short* __restrict__ pre,
    const float* __restrict__ bias,
    float* __restrict__ out, int N)
{
    __shared__ int2 srec[ACAP];             // 11.3 KB staged raw
    __shared__ int2 srt[ACAP];              // 11.3 KB row-sorted
    __shared__ int lcnt[32];
    __shared__ int lstart[32];
    __shared__ int lcur[32];

    const int b = blockIdx.x;
    const int tid = threadIdx.x;

    int n0 = cur[2 * b];     if (n0 > BCAP) n0 = BCAP;
    int n1 = cur[2 * b + 1]; if (n1 > BCAP) n1 = BCAP;
    const int total = n0 + n1;
    const int base0 = (2 * b) * BCAP, base1 = (2 * b + 1) * BCAP;

    if (tid < 32) lcnt[tid] = 0;
    __syncthreads();

    // stage + per-row counts (int LDS atomics)
    for (int i = tid; i < total; i += 256) {
        int2 r = (i < n0) ? recs[base0 + i] : recs[base1 + i - n0];
        srec[i] = r;
        atomicAdd(&lcnt[(r.x >> 17) & 31], 1);
    }
    __syncthreads();

    // wave 0 lanes 0-31: shfl exclusive scan of 32 counters
    if (tid < 32) {
        int cme = lcnt[tid];
        int p = cme;
#pragma unroll
        for (int o = 1; o < 32; o <<= 1) {
            int t = __shfl_up(p, o);
            if (tid >= o) p += t;
        }
        lstart[tid] = p - cme;
        lcur[tid] = p - cme;
    }
    __syncthreads();

    // scatter full records sorted by row
    for (int i = tid; i < total; i += 256) {
        int2 r = srec[i];
        srt[atomicAdd(&lcur[(r.x >> 17) & 31], 1)] = r;
    }
    __syncthreads();

    // gather: wave wv owns rows wv*8 .. wv*8+7; both adjacencies in one run
    const int wv = tid >> 6;
    const int lane = tid & 63;
    const float2 bi = *(const float2*)&bias[lane * 2];

#define GA(r) (*(const unsigned*)&pre[((r).x & 0x1ffff) * 128 + 2 * lane])
#define ACC(r, u) { float v = __int_as_float((r).y);                    \
        acc.x = fmaf(v, __uint_as_float((u) << 16), acc.x);             \
        acc.y = fmaf(v, __uint_as_float((u) & 0xffff0000u), acc.y); }

    for (int t = 0; t < 8; ++t) {
        const int rl = wv * 8 + t;
        const int s = lstart[rl];
        const int e = s + lcnt[rl];
        float2 acc = make_float2(0.f, 0.f);
        int j = s;
        for (; j + 8 <= e; j += 8) {
            int2 r0 = srt[j], r1 = srt[j + 1], r2 = srt[j + 2], r3 = srt[j + 3];
            int2 r4 = srt[j + 4], r5 = srt[j + 5], r6 = srt[j + 6], r7 = srt[j + 7];
            unsigned u0 = GA(r0), u1 = GA(r1), u2 = GA(r2), u3 = GA(r3);
            unsigned u4 = GA(r4), u5 = GA(r5), u6 = GA(r6), u7 = GA(r7);
            ACC(r0, u0); ACC(r1, u1); ACC(r2, u2); ACC(r3, u3);
            ACC(r4, u4); ACC(r5, u5); ACC(r6, u6); ACC(r7, u7);
        }
        for (; j + 4 <= e; j += 4) {
            int2 r0 = srt[j], r1 = srt[j + 1], r2 = srt[j + 2], r3 = srt[j + 3];
            unsigned u0 = GA(r0), u1 = GA(r1), u2 = GA(r2), u3 = GA(r3);
            ACC(r0, u0); ACC(r1, u1); ACC(r2, u2); ACC(r3, u3);
        }
        for (; j < e; ++j) {
            int2 r0 = srt[j];
            unsigned u0 = GA(r0);
            ACC(r0, u0);
        }
        int row = b * BROWS + rl;
        if (row < N) {
            float2 o;
            o.x = fmaxf(acc.x + bi.x, 0.f);
            o.y = fmaxf(acc.y + bi.y, 0.f);
            *(float2*)&out[row * 128 + 2 * lane] = o;
        }
    }
#undef GA
#undef ACC
}

extern "C" void kernel_launch(void* const* d_in, const int* in_sizes, int n_in,
                              void* d_out, int out_size, void* d_ws, size_t ws_size,
                              hipStream_t stream) {
    const float* x    = (const float*)d_in[0];
    const float* W0   = (const float*)d_in[1];
    const float* W1   = (const float*)d_in[2];
    const float* bias = (const float*)d_in[3];
    const float* ev0  = (const float*)d_in[4];
    const float* ev1  = (const float*)d_in[5];
    const int*   ei0  = (const int*)d_in[6];
    const int*   ei1  = (const int*)d_in[7];
    float* out = (float*)d_out;

    const int N = in_sizes[0] / 128;      // 50000
    const int E = in_sizes[4];            // 800000
    const int NBINS2 = NBUCK * 2;         // 3126

    // Workspace layout
    char* w = (char*)d_ws;
    unsigned short* pre = (unsigned short*)w;   w += (size_t)2 * PREROWS * 128 * 2;  // 33.5 MB
    unsigned short* wt0 = (unsigned short*)w;   w += (size_t)128 * 128 * 2;
    unsigned short* wt1 = (unsigned short*)w;   w += (size_t)128 * 128 * 2;
    int* cur = (int*)w;                         w += (size_t)NBINS2 * 4;
    int2* recs = (int2*)w;                      w += (size_t)NBINS2 * BCAP * 8;      // 17.6 MB

    // Phase 0: W -> bf16 transposed + zero cur (4 blocks)
    convert_w_kernel<<<4, 256, 0, stream>>>(W0, W1, wt0, wt1, cur, NBINS2);

    // Phase 1: fused MFMA GEMM (x read once, both adjacencies per block)
    gemm_fused_kernel<<<N / 16, 512, 0, stream>>>(x, wt0, wt1, pre, N);

    // Phase 2: binned fill (392 blocks)
    dim3 fgrid((E + FT - 1) / FT, 2);
    fill4_kernel<<<fgrid, 1024, 0, stream>>>(ei0, ei1, ev0, ev1, cur, recs, E);

    // Phase 3: bucket-sorted gather aggregation + bias + relu
    aggregate9_kernel<<<NBUCK, 256, 0, stream>>>(cur, recs, pre, bias, out, N);
}

// Round 12
// 233.351 us; speedup vs baseline: 5.8846x; 1.0241x over previous
//
#include <hip/hip_runtime.h>
#include <hip/hip_bf16.h>

// GCN layer: out = relu( A0 @ (X W0) + A1 @ (X W1) + bias )
// N=50000, D=128, E=800000 per adjacency, fp32 in/out, COO edges.
//
// R12 (attack the non-aggregate phases; aggregate9 kept verbatim at 62.5us):
//   convert     x -> bf16 (vectorized) + W0/W1 -> bf16 transposed + zero cur,
//               all one dispatch. Removes gemm's in-register f2bf storm
//               (R10/R11 cost ~20-25us vs R8's split converts).
//   gemm_fused  A-frag = single bf16x8 load from xb; LDS-staged C stores.
//   fill4       FT=16384 (10.5-record runs -> ~1.8x write amp, vs 3x at 4096).
//   aggregate9  verbatim R11: 32-key counting sort, 8x-unrolled register-
//               accumulate gather (~62.5us ~= the random-gather ceiling:
//               FETCH pinned 177MB @ ~3.3TB/s across R8/R10/R11 variants).
// NEVER use fp32 LDS atomics in the per-record loop (R4: 1234us, R9: 1216us).

#define BROWS 32                   // bucket = 32 dst rows
#define NBUCK 1563                 // ceil(50000/32)
#define BCAP 704                   // records per (bucket,adj); mean 512, +8.5 sigma
#define ACAP (2 * BCAP)
#define FT 16384                   // fill tile (edges per block)
#define PREROWS 65536              // adj stride in unified pre

typedef __attribute__((ext_vector_type(8))) short bf16x8;
typedef __attribute__((ext_vector_type(4))) float f32x4;

__device__ inline unsigned short f2bf(float f) {
    union { float f; unsigned u; } v; v.f = f;
    unsigned r = v.u + 0x7fff + ((v.u >> 16) & 1);   // round-nearest-even
    return (unsigned short)(r >> 16);
}

// blocks [0,nxb): x fp32->bf16. nxb,nxb+1: W transpose. nxb+2,nxb+3: zero cur.
__global__ __launch_bounds__(256) void convert_kernel(
    const float* __restrict__ x, const float* __restrict__ W0,
    const float* __restrict__ W1,
    unsigned short* __restrict__ xb,
    unsigned short* __restrict__ wt0, unsigned short* __restrict__ wt1,
    int* __restrict__ cur, int ncur, int nxb, int nx4)
{
    int bid = blockIdx.x;
    int tid = threadIdx.x;
    if (bid < nxb) {
        int i4 = bid * 256 + tid;
        if (i4 < nx4) {
            float4 v = *(const float4*)&x[i4 * 4];
            ushort4 s;
            s.x = f2bf(v.x); s.y = f2bf(v.y); s.z = f2bf(v.z); s.w = f2bf(v.w);
            *(ushort4*)&xb[i4 * 4] = s;
        }
        return;
    }
    int r = bid - nxb;
    if (r < 2) {
        const float* __restrict__ W = r ? W1 : W0;
        unsigned short* __restrict__ wt = r ? wt1 : wt0;
        for (int i = tid; i < 128 * 128; i += 256) {
            int k = i >> 7, n = i & 127;
            wt[n * 128 + k] = f2bf(W[i]);
        }
        return;
    }
    int half = (ncur + 1) / 2;
    int base = (r - 2) * half;
    for (int i = tid; i < half; i += 256)
        if (base + i < ncur) cur[base + i] = 0;
}

// One block: 16 x-rows, BOTH adjacencies. Waves 0-3 -> W0 cols, 4-7 -> W1.
// A: m=lane&15, k=quad*8+j ; B(from Wt): n=lane&15, k=quad*8+j ;
// C/D: col=lane&15, row=quad*4+reg. C staged via LDS -> 16-B global stores.
__global__ __launch_bounds__(512) void gemm_fused_kernel(
    const unsigned short* __restrict__ xb,
    const unsigned short* __restrict__ wt0,
    const unsigned short* __restrict__ wt1,
    unsigned short* __restrict__ pre,    // unified: adj*PREROWS + row
    int N)
{
    __shared__ short ctile[8][16][40];   // per-wave 16x32 C tile (+pad)

    const int w = threadIdx.x >> 6;
    const int lane = threadIdx.x & 63;
    const int adj = w >> 2;
    const int wq = w & 3;
    const int m0 = blockIdx.x * 16;
    const unsigned short* __restrict__ wt = adj ? wt1 : wt0;
    unsigned short* __restrict__ po = pre + (size_t)adj * PREROWS * 128;
    const int l15 = lane & 15;
    const int quad = lane >> 4;
    const int nA = wq * 32 + l15;

    f32x4 c0 = {0.f, 0.f, 0.f, 0.f};
    f32x4 c1 = {0.f, 0.f, 0.f, 0.f};
#pragma unroll
    for (int k0 = 0; k0 < 128; k0 += 32) {
        bf16x8 a  = *(const bf16x8*)&xb[(m0 + l15) * 128 + k0 + quad * 8];
        bf16x8 b0 = *(const bf16x8*)&wt[nA * 128 + k0 + quad * 8];
        bf16x8 b1 = *(const bf16x8*)&wt[(nA + 16) * 128 + k0 + quad * 8];
        c0 = __builtin_amdgcn_mfma_f32_16x16x32_bf16(a, b0, c0, 0, 0, 0);
        c1 = __builtin_amdgcn_mfma_f32_16x16x32_bf16(a, b1, c1, 0, 0, 0);
    }

    // stage C into wave-private LDS tile (wave-internal dep: no barrier)
#pragma unroll
    for (int i = 0; i < 4; ++i) {
        ctile[w][quad * 4 + i][l15]      = (short)f2bf(c0[i]);
        ctile[w][quad * 4 + i][16 + l15] = (short)f2bf(c1[i]);
    }
    // read back coalesced: lane -> row lane>>2, col group (lane&3)*8
    const int rr = lane >> 2, cg = (lane & 3) * 8;
    ushort4 s0 = *(ushort4*)&ctile[w][rr][cg];
    ushort4 s1 = *(ushort4*)&ctile[w][rr][cg + 4];
    int row = m0 + rr;                        // N % 16 == 0, always < N
    *(ushort4*)&po[row * 128 + wq * 32 + cg] = s0;
    *(ushort4*)&po[row * 128 + wq * 32 + cg + 4] = s1;
}

// Fixed-capacity binned fill, bin = (dst>>5)*2 + adj. Per-record rank from
// LDS int hist atomicAdd; one global cursor add per (block,key) ->
// run-contiguous writes (~10.5-rec runs). Record = {rl<<17|adj<<16|src, val}.
__global__ __launch_bounds__(1024) void fill4_kernel(
    const int* __restrict__ ei0, const int* __restrict__ ei1,
    const float* __restrict__ ev0, const float* __restrict__ ev1,
    int* __restrict__ cur, int2* __restrict__ recs, int E)
{
    const int a = blockIdx.y;
    const int* __restrict__ ei = a ? ei1 : ei0;
    const float* __restrict__ ev = a ? ev1 : ev0;

    __shared__ int lcnt[NBUCK];
    __shared__ int gbase[NBUCK];
    __shared__ int glim[NBUCK];
    for (int k = threadIdx.x; k < NBUCK; k += 1024) lcnt[k] = 0;
    __syncthreads();

    const int e0 = blockIdx.x * FT;
    unsigned ds[16];
    float val[16];
    short rank[16];
#pragma unroll
    for (int j = 0; j < 16; ++j) {
        int e = e0 + j * 1024 + threadIdx.x;
        if (e < E) {
            int d = ei[e];
            int s = ei[E + e];
            ds[j] = ((unsigned)d << 16) | (unsigned)s;   // d < 50000 < 65536
            val[j] = ev[e];
            rank[j] = (short)atomicAdd(&lcnt[d >> 5], 1);
        } else ds[j] = 0xffffffffu;                      // d=65535 impossible
    }
    __syncthreads();

    for (int k = threadIdx.x; k < NBUCK; k += 1024) {
        int c = lcnt[k];
        int base = 0, lim = 0;
        if (c > 0) {
            int bin = k * 2 + a;
            int b0 = atomicAdd(&cur[bin], c);
            lim = BCAP - b0; if (lim < 0) lim = 0;       // overflow guard
            base = bin * BCAP + b0;
        }
        gbase[k] = base;
        glim[k] = lim;
    }
    __syncthreads();

#pragma unroll
    for (int j = 0; j < 16; ++j) {
        if (ds[j] != 0xffffffffu) {
            int key = ds[j] >> 21;                       // dst>>5
            int r = rank[j];
            if (r < glim[key]) {
                int rl = (ds[j] >> 16) & 31;
                recs[gbase[key] + r] =
                    make_int2((rl << 17) | (a << 16) | (ds[j] & 0xffff),
                              __float_as_int(val[j]));
            }
        }
    }
}

// One block per 32-row bucket (256 thr = 4 waves, wave wv -> rows wv*8..+7).
// Stage records in LDS, counting-sort FULL records by row (32 keys), then
// 8x-unrolled independent gathers from the unified pre, register accumulate,
// fused bias+relu writeout. (Verbatim R11 structure: measured 62.5us.)
__global__ __launch_bounds__(256, 6) void aggregate9_kernel(
    const int* __restrict__ cur, const int2* __restrict__ recs,
    const unsigned short* __restrict__ pre,
    const float* __restrict__ bias,
    float* __restrict__ out, int N)
{
    __shared__ int2 srec[ACAP];             // 11.3 KB staged raw
    __shared__ int2 srt[ACAP];              // 11.3 KB row-sorted
    __shared__ int lcnt[32];
    __shared__ int lstart[32];
    __shared__ int lcur[32];

    const int b = blockIdx.x;
    const int tid = threadIdx.x;

    int n0 = cur[2 * b];     if (n0 > BCAP) n0 = BCAP;
    int n1 = cur[2 * b + 1]; if (n1 > BCAP) n1 = BCAP;
    const int total = n0 + n1;
    const int base0 = (2 * b) * BCAP, base1 = (2 * b + 1) * BCAP;

    if (tid < 32) lcnt[tid] = 0;
    __syncthreads();

    // stage + per-row counts (int LDS atomics)
    for (int i = tid; i < total; i += 256) {
        int2 r = (i < n0) ? recs[base0 + i] : recs[base1 + i - n0];
        srec[i] = r;
        atomicAdd(&lcnt[(r.x >> 17) & 31], 1);
    }
    __syncthreads();

    // wave 0 lanes 0-31: shfl exclusive scan of 32 counters
    if (tid < 32) {
        int cme = lcnt[tid];
        int p = cme;
#pragma unroll
        for (int o = 1; o < 32; o <<= 1) {
            int t = __shfl_up(p, o);
            if (tid >= o) p += t;
        }
        lstart[tid] = p - cme;
        lcur[tid] = p - cme;
    }
    __syncthreads();

    // scatter full records sorted by row
    for (int i = tid; i < total; i += 256) {
        int2 r = srec[i];
        srt[atomicAdd(&lcur[(r.x >> 17) & 31], 1)] = r;
    }
    __syncthreads();

    // gather: wave wv owns rows wv*8 .. wv*8+7; both adjacencies in one run
    const int wv = tid >> 6;
    const int lane = tid & 63;
    const float2 bi = *(const float2*)&bias[lane * 2];

#define GA(r) (*(const unsigned*)&pre[((r).x & 0x1ffff) * 128 + 2 * lane])
#define ACC(r, u) { float v = __int_as_float((r).y);                    \
        acc.x = fmaf(v, __uint_as_float((u) << 16), acc.x);             \
        acc.y = fmaf(v, __uint_as_float((u) & 0xffff0000u), acc.y); }

    for (int t = 0; t < 8; ++t) {
        const int rl = wv * 8 + t;
        const int s = lstart[rl];
        const int e = s + lcnt[rl];
        float2 acc = make_float2(0.f, 0.f);
        int j = s;
        for (; j + 8 <= e; j += 8) {
            int2 r0 = srt[j], r1 = srt[j + 1], r2 = srt[j + 2], r3 = srt[j + 3];
            int2 r4 = srt[j + 4], r5 = srt[j + 5], r6 = srt[j + 6], r7 = srt[j + 7];
            unsigned u0 = GA(r0), u1 = GA(r1), u2 = GA(r2), u3 = GA(r3);
            unsigned u4 = GA(r4), u5 = GA(r5), u6 = GA(r6), u7 = GA(r7);
            ACC(r0, u0); ACC(r1, u1); ACC(r2, u2); ACC(r3, u3);
            ACC(r4, u4); ACC(r5, u5); ACC(r6, u6); ACC(r7, u7);
        }
        for (; j + 4 <= e; j += 4) {
            int2 r0 = srt[j], r1 = srt[j + 1], r2 = srt[j + 2], r3 = srt[j + 3];
            unsigned u0 = GA(r0), u1 = GA(r1), u2 = GA(r2), u3 = GA(r3);
            ACC(r0, u0); ACC(r1, u1); ACC(r2, u2); ACC(r3, u3);
        }
        for (; j < e; ++j) {
            int2 r0 = srt[j];
            unsigned u0 = GA(r0);
            ACC(r0, u0);
        }
        int row = b * BROWS + rl;
        if (row < N) {
            float2 o;
            o.x = fmaxf(acc.x + bi.x, 0.f);
            o.y = fmaxf(acc.y + bi.y, 0.f);
            *(float2*)&out[row * 128 + 2 * lane] = o;
        }
    }
#undef GA
#undef ACC
}

extern "C" void kernel_launch(void* const* d_in, const int* in_sizes, int n_in,
                              void* d_out, int out_size, void* d_ws, size_t ws_size,
                              hipStream_t stream) {
    const float* x    = (const float*)d_in[0];
    const float* W0   = (const float*)d_in[1];
    const float* W1   = (const float*)d_in[2];
    const float* bias = (const float*)d_in[3];
    const float* ev0  = (const float*)d_in[4];
    const float* ev1  = (const float*)d_in[5];
    const int*   ei0  = (const int*)d_in[6];
    const int*   ei1  = (const int*)d_in[7];
    float* out = (float*)d_out;

    const int N = in_sizes[0] / 128;      // 50000
    const int E = in_sizes[4];            // 800000
    const int NX = N * 128;               // 6.4M
    const int NBINS2 = NBUCK * 2;         // 3126

    // Workspace layout
    char* w = (char*)d_ws;
    unsigned short* pre = (unsigned short*)w;   w += (size_t)2 * PREROWS * 128 * 2;  // 33.5 MB
    unsigned short* xb  = (unsigned short*)w;   w += (size_t)NX * 2;                 // 12.8 MB
    unsigned short* wt0 = (unsigned short*)w;   w += (size_t)128 * 128 * 2;
    unsigned short* wt1 = (unsigned short*)w;   w += (size_t)128 * 128 * 2;
    int* cur = (int*)w;                         w += (size_t)NBINS2 * 4;
    int2* recs = (int2*)w;                      w += (size_t)NBINS2 * BCAP * 8;      // 17.6 MB

    // Phase 0: x -> bf16, W -> bf16 transposed, zero cur (one dispatch)
    const int nx4 = NX / 4;
    const int nxb = (nx4 + 255) / 256;    // 6250
    convert_kernel<<<nxb + 4, 256, 0, stream>>>(x, W0, W1, xb, wt0, wt1,
                                                cur, NBINS2, nxb, nx4);

    // Phase 1: fused MFMA GEMM (both adjacencies per block)
    gemm_fused_kernel<<<N / 16, 512, 0, stream>>>(xb, wt0, wt1, pre, N);

    // Phase 2: binned fill (grid (49,2))
    dim3 fgrid((E + FT - 1) / FT, 2);
    fill4_kernel<<<fgrid, 1024, 0, stream>>>(ei0, ei1, ev0, ev1, cur, recs, E);

    // Phase 3: bucket-sorted gather aggregation + bias + relu
    aggregate9_kernel<<<NBUCK, 256, 0, stream>>>(cur, recs, pre, bias, out, N);
}

// Round 13
// 201.290 us; speedup vs baseline: 6.8219x; 1.1593x over previous
//
#include <hip/hip_runtime.h>
#include <hip/hip_bf16.h>

// GCN layer: out = relu( A0 @ (X W0) + A1 @ (X W1) + bias )
// N=50000, D=128, E=800000 per adjacency, fp32 in/out, COO edges.
//
// R13:
//   prep        W0/W1 -> bf16 transposed (8 blocks, k-split) + zero cur
//   gemm_fused  reads fp32 x, converts ONCE per block into LDS bf16 A-tile
//               (not 8x per-wave like R10); MFMA 16x16x32; LDS-staged C.
//   fill5       LDS counting-sort of 8192 edges per block -> write-out with
//               consecutive threads at consecutive addresses (coalesced).
//   aggregate9  verbatim R11/R12 (measured 61us, FETCH pinned ~177MB =
//               the random-gather ceiling across 4 structural variants).
// NEVER use fp32 LDS atomics in the per-record loop (R4: 1234us, R9: 1216us).

#define BROWS 32                   // bucket = 32 dst rows
#define NBUCK 1563                 // ceil(50000/32)
#define NB2 2048                   // padded bin count for fill5 scan
#define BCAP 704                   // records per (bucket,adj); mean 512, +8.5 sigma
#define ACAP (2 * BCAP)
#define FT5 8192                   // fill tile (edges per block)
#define PREROWS 65536              // adj stride in unified pre

typedef __attribute__((ext_vector_type(8))) short bf16x8;
typedef __attribute__((ext_vector_type(4))) float f32x4;

__device__ inline unsigned short f2bf(float f) {
    union { float f; unsigned u; } v; v.f = f;
    unsigned r = v.u + 0x7fff + ((v.u >> 16) & 1);   // round-nearest-even
    return (unsigned short)(r >> 16);
}

// blocks 0..7: W transpose (4 k-slices x 2 Ws). block 8: zero cur.
__global__ __launch_bounds__(256) void prep_kernel(
    const float* __restrict__ W0, const float* __restrict__ W1,
    unsigned short* __restrict__ wt0, unsigned short* __restrict__ wt1,
    int* __restrict__ cur, int ncur)
{
    const int bid = blockIdx.x;
    const int tid = threadIdx.x;
    if (bid >= 8) {
        for (int i = tid; i < ncur; i += 256) cur[i] = 0;
        return;
    }
    const int which = bid >> 2;
    const int k0 = (bid & 3) * 32;
    const float* __restrict__ W = which ? W1 : W0;
    unsigned short* __restrict__ wt = which ? wt1 : wt0;
    for (int i = tid; i < 32 * 128; i += 256) {
        int k = k0 + (i >> 7), n = i & 127;
        wt[n * 128 + k] = f2bf(W[k * 128 + n]);
    }
}

// One block: 16 x-rows, BOTH adjacencies. Waves 0-3 -> W0 cols, 4-7 -> W1.
// Block stages x rows fp32->bf16 into LDS once; waves ds_read A-frags.
// A: m=lane&15, k=quad*8+j ; B(from Wt): n=lane&15, k=quad*8+j ;
// C/D: col=lane&15, row=quad*4+reg. C staged via LDS -> 16-B global stores.
__global__ __launch_bounds__(512) void gemm_fused_kernel(
    const float* __restrict__ x,
    const unsigned short* __restrict__ wt0,
    const unsigned short* __restrict__ wt1,
    unsigned short* __restrict__ pre,    // unified: adj*PREROWS + row
    int N)
{
    __shared__ unsigned short sA[16][136];  // bf16 A-tile, pad: 272B row (2-way banks)
    __shared__ short ctile[8][16][40];      // per-wave 16x32 C tile (+pad)

    const int tid = threadIdx.x;
    const int m0 = blockIdx.x * 16;

    // stage A: 512 float4 loads (1 per thread), convert, store 8B to LDS
    {
        int r = tid >> 5;                 // 32 float4 per row
        int c4 = (tid & 31) << 2;
        float4 v = *(const float4*)&x[(m0 + r) * 128 + c4];
        ushort4 s;
        s.x = f2bf(v.x); s.y = f2bf(v.y); s.z = f2bf(v.z); s.w = f2bf(v.w);
        *(ushort4*)&sA[r][c4] = s;
    }
    __syncthreads();

    const int w = tid >> 6;
    const int lane = tid & 63;
    const int adj = w >> 2;
    const int wq = w & 3;
    const unsigned short* __restrict__ wt = adj ? wt1 : wt0;
    unsigned short* __restrict__ po = pre + (size_t)adj * PREROWS * 128;
    const int l15 = lane & 15;
    const int quad = lane >> 4;
    const int nA = wq * 32 + l15;

    f32x4 c0 = {0.f, 0.f, 0.f, 0.f};
    f32x4 c1 = {0.f, 0.f, 0.f, 0.f};
#pragma unroll
    for (int k0 = 0; k0 < 128; k0 += 32) {
        union { bf16x8 v; ushort4 h[2]; } au;
        au.h[0] = *(const ushort4*)&sA[l15][k0 + quad * 8];
        au.h[1] = *(const ushort4*)&sA[l15][k0 + quad * 8 + 4];
        bf16x8 b0 = *(const bf16x8*)&wt[nA * 128 + k0 + quad * 8];
        bf16x8 b1 = *(const bf16x8*)&wt[(nA + 16) * 128 + k0 + quad * 8];
        c0 = __builtin_amdgcn_mfma_f32_16x16x32_bf16(au.v, b0, c0, 0, 0, 0);
        c1 = __builtin_amdgcn_mfma_f32_16x16x32_bf16(au.v, b1, c1, 0, 0, 0);
    }

    // stage C into wave-private LDS tile (wave-internal dep: no barrier)
#pragma unroll
    for (int i = 0; i < 4; ++i) {
        ctile[w][quad * 4 + i][l15]      = (short)f2bf(c0[i]);
        ctile[w][quad * 4 + i][16 + l15] = (short)f2bf(c1[i]);
    }
    const int rr = lane >> 2, cg = (lane & 3) * 8;
    ushort4 s0 = *(ushort4*)&ctile[w][rr][cg];
    ushort4 s1 = *(ushort4*)&ctile[w][rr][cg + 4];
    int row = m0 + rr;                        // N % 16 == 0, always < N
    *(ushort4*)&po[row * 128 + wq * 32 + cg] = s0;
    *(ushort4*)&po[row * 128 + wq * 32 + cg + 4] = s1;
}

// LDS counting-sort fill: block sorts its 8192 edges by bucket (dst>>5) in
// LDS, reserves one global range per (block,bucket), then writes out with
// consecutive threads at consecutive global addresses (coalesced runs).
// Record = { rl<<17 | adj<<16 | src, val }; bin = bucket*2 + adj.
__global__ __launch_bounds__(1024) void fill5_kernel(
    const int* __restrict__ ei0, const int* __restrict__ ei1,
    const float* __restrict__ ev0, const float* __restrict__ ev1,
    int* __restrict__ cur, int2* __restrict__ recs, int E)
{
    __shared__ int2 srt[FT5];                 // 64 KB sorted records
    __shared__ unsigned short skey[FT5];      // 16 KB bucket of each record
    __shared__ int lcnt[NB2];                 // 8 KB
    __shared__ int bstart[NB2];               // 8 KB
    __shared__ int lcur[NB2];                 // 8 KB
    __shared__ int gpos[NBUCK];               // 6.3 KB global base per bucket
    __shared__ int glim[NBUCK];               // 6.3 KB
    __shared__ int part[1024];                // 4 KB scan partials

    const int a = blockIdx.y;
    const int* __restrict__ ei = a ? ei1 : ei0;
    const float* __restrict__ ev = a ? ev1 : ev0;
    const int tid = threadIdx.x;
    const int e0 = blockIdx.x * FT5;

    lcnt[tid] = 0; lcnt[tid + 1024] = 0;
    __syncthreads();

    int2 rec[8];
    int key8[8];
#pragma unroll
    for (int j = 0; j < 8; ++j) {
        int e = e0 + j * 1024 + tid;
        if (e < E) {
            int d = ei[e];
            int s = ei[E + e];
            key8[j] = d >> 5;
            rec[j] = make_int2(((d & 31) << 17) | (a << 16) | s,
                               __float_as_int(ev[e]));
            atomicAdd(&lcnt[key8[j]], 1);
        } else key8[j] = -1;
    }
    __syncthreads();

    // exclusive scan over 2048 bins (2 per thread)
    int c0 = lcnt[2 * tid], c1 = lcnt[2 * tid + 1];
    int tsum = c0 + c1;
    part[tid] = tsum;
    __syncthreads();
    for (int o = 1; o < 1024; o <<= 1) {
        int t = (tid >= o) ? part[tid - o] : 0;
        __syncthreads();
        part[tid] += t;
        __syncthreads();
    }
    int run = part[tid] - tsum;
    const int total = part[1023];
    bstart[2 * tid] = run; lcur[2 * tid] = run;
    bstart[2 * tid + 1] = run + c0; lcur[2 * tid + 1] = run + c0;

    // reserve global ranges (one atomic per nonzero (block,bucket))
#pragma unroll
    for (int h = 0; h < 2; ++h) {
        int k = 2 * tid + h;
        int c = h ? c1 : c0;
        if (k < NBUCK && c > 0) {
            int bin = k * 2 + a;
            int g = atomicAdd(&cur[bin], c);
            int lim = BCAP - g; if (lim < 0) lim = 0;    // overflow guard
            gpos[k] = bin * BCAP + g;
            glim[k] = lim;
        }
    }
    __syncthreads();

    // scatter into LDS sorted by bucket
#pragma unroll
    for (int j = 0; j < 8; ++j) {
        if (key8[j] >= 0) {
            int p = atomicAdd(&lcur[key8[j]], 1);
            srt[p] = rec[j];
            skey[p] = (unsigned short)key8[j];
        }
    }
    __syncthreads();

    // coalesced write-out: consecutive i -> consecutive global addr per run
    for (int i = tid; i < total; i += 1024) {
        int k = skey[i];
        int r = i - bstart[k];
        if (r < glim[k]) recs[gpos[k] + r] = srt[i];
    }
}

// One block per 32-row bucket (256 thr = 4 waves, wave wv -> rows wv*8..+7).
// Stage records in LDS, counting-sort FULL records by row (32 keys), then
// 8x-unrolled independent gathers from the unified pre, register accumulate,
// fused bias+relu writeout. (Verbatim R11/R12 structure: measured 61-62.5us.)
__global__ __launch_bounds__(256, 6) void aggregate9_kernel(
    const int* __restrict__ cur, const int2* __restrict__ recs,
    const unsigned short* __restrict__ pre,
    const float* __restrict__ bias,
    float* __restrict__ out, int N)
{
    __shared__ int2 srec[ACAP];             // 11.3 KB staged raw
    __shared__ int2 srt[ACAP];              // 11.3 KB row-sorted
    __shared__ int lcnt[32];
    __shared__ int lstart[32];
    __shared__ int lcur[32];

    const int b = blockIdx.x;
    const int tid = threadIdx.x;

    int n0 = cur[2 * b];     if (n0 > BCAP) n0 = BCAP;
    int n1 = cur[2 * b + 1]; if (n1 > BCAP) n1 = BCAP;
    const int total = n0 + n1;
    const int base0 = (2 * b) * BCAP, base1 = (2 * b + 1) * BCAP;

    if (tid < 32) lcnt[tid] = 0;
    __syncthreads();

    // stage + per-row counts (int LDS atomics)
    for (int i = tid; i < total; i += 256) {
        int2 r = (i < n0) ? recs[base0 + i] : recs[base1 + i - n0];
        srec[i] = r;
        atomicAdd(&lcnt[(r.x >> 17) & 31], 1);
    }
    __syncthreads();

    // wave 0 lanes 0-31: shfl exclusive scan of 32 counters
    if (tid < 32) {
        int cme = lcnt[tid];
        int p = cme;
#pragma unroll
        for (int o = 1; o < 32; o <<= 1) {
            int t = __shfl_up(p, o);
            if (tid >= o) p += t;
        }
        lstart[tid] = p - cme;
        lcur[tid] = p - cme;
    }
    __syncthreads();

    // scatter full records sorted by row
    for (int i = tid; i < total; i += 256) {
        int2 r = srec[i];
        srt[atomicAdd(&lcur[(r.x >> 17) & 31], 1)] = r;
    }
    __syncthreads();

    // gather: wave wv owns rows wv*8 .. wv*8+7; both adjacencies in one run
    const int wv = tid >> 6;
    const int lane = tid & 63;
    const float2 bi = *(const float2*)&bias[lane * 2];

#define GA(r) (*(const unsigned*)&pre[((r).x & 0x1ffff) * 128 + 2 * lane])
#define ACC(r, u) { float v = __int_as_float((r).y);                    \
        acc.x = fmaf(v, __uint_as_float((u) << 16), acc.x);             \
        acc.y = fmaf(v, __uint_as_float((u) & 0xffff0000u), acc.y); }

    for (int t = 0; t < 8; ++t) {
        const int rl = wv * 8 + t;
        const int s = lstart[rl];
        const int e = s + lcnt[rl];
        float2 acc = make_float2(0.f, 0.f);
        int j = s;
        for (; j + 8 <= e; j += 8) {
            int2 r0 = srt[j], r1 = srt[j + 1], r2 = srt[j + 2], r3 = srt[j + 3];
            int2 r4 = srt[j + 4], r5 = srt[j + 5], r6 = srt[j + 6], r7 = srt[j + 7];
            unsigned u0 = GA(r0), u1 = GA(r1), u2 = GA(r2), u3 = GA(r3);
            unsigned u4 = GA(r4), u5 = GA(r5), u6 = GA(r6), u7 = GA(r7);
            ACC(r0, u0); ACC(r1, u1); ACC(r2, u2); ACC(r3, u3);
            ACC(r4, u4); ACC(r5, u5); ACC(r6, u6); ACC(r7, u7);
        }
        for (; j + 4 <= e; j += 4) {
            int2 r0 = srt[j], r1 = srt[j + 1], r2 = srt[j + 2], r3 = srt[j + 3];
            unsigned u0 = GA(r0), u1 = GA(r1), u2 = GA(r2), u3 = GA(r3);
            ACC(r0, u0); ACC(r1, u1); ACC(r2, u2); ACC(r3, u3);
        }
        for (; j < e; ++j) {
            int2 r0 = srt[j];
            unsigned u0 = GA(r0);
            ACC(r0, u0);
        }
        int row = b * BROWS + rl;
        if (row < N) {
            float2 o;
            o.x = fmaxf(acc.x + bi.x, 0.f);
            o.y = fmaxf(acc.y + bi.y, 0.f);
            *(float2*)&out[row * 128 + 2 * lane] = o;
        }
    }
#undef GA
#undef ACC
}

extern "C" void kernel_launch(void* const* d_in, const int* in_sizes, int n_in,
                              void* d_out, int out_size, void* d_ws, size_t ws_size,
                              hipStream_t stream) {
    const float* x    = (const float*)d_in[0];
    const float* W0   = (const float*)d_in[1];
    const float* W1   = (const float*)d_in[2];
    const float* bias = (const float*)d_in[3];
    const float* ev0  = (const float*)d_in[4];
    const float* ev1  = (const float*)d_in[5];
    const int*   ei0  = (const int*)d_in[6];
    const int*   ei1  = (const int*)d_in[7];
    float* out = (float*)d_out;

    const int N = in_sizes[0] / 128;      // 50000
    const int E = in_sizes[4];            // 800000
    const int NBINS2 = NBUCK * 2;         // 3126

    // Workspace layout
    char* w = (char*)d_ws;
    unsigned short* pre = (unsigned short*)w;   w += (size_t)2 * PREROWS * 128 * 2;  // 33.5 MB
    unsigned short* wt0 = (unsigned short*)w;   w += (size_t)128 * 128 * 2;
    unsigned short* wt1 = (unsigned short*)w;   w += (size_t)128 * 128 * 2;
    int* cur = (int*)w;                         w += (size_t)NBINS2 * 4;
    int2* recs = (int2*)w;                      w += (size_t)NBINS2 * BCAP * 8;      // 17.6 MB

    // Phase 0: W -> bf16 transposed + zero cur (one 9-block dispatch)
    prep_kernel<<<9, 256, 0, stream>>>(W0, W1, wt0, wt1, cur, NBINS2);

    // Phase 1: fused MFMA GEMM (x converted once per block in LDS)
    gemm_fused_kernel<<<N / 16, 512, 0, stream>>>(x, wt0, wt1, pre, N);

    // Phase 2: LDS counting-sort fill (grid (98,2), coalesced write-out)
    dim3 fgrid((E + FT5 - 1) / FT5, 2);
    fill5_kernel<<<fgrid, 1024, 0, stream>>>(ei0, ei1, ev0, ev1, cur, recs, E);

    // Phase 3: bucket-sorted gather aggregation + bias + relu
    aggregate9_kernel<<<NBUCK, 256, 0, stream>>>(cur, recs, pre, bias, out, N);
}